// Round 2
// baseline (747.410 us; speedup 1.0000x reference)
//
#include <hip/hip_runtime.h>

#define NN 8192
#define FIN 128
#define FOUT 64
#define LRELU_ALPHA 0.2f

// Kernel A: wh = h @ W (fp32), src[i] = wh[i].a1 + edge[i]*(wedge.a3), dst[i] = wh[i].a2
__global__ __launch_bounds__(256) void gat_prep(
    const float* __restrict__ h,      // 8192x128
    const float* __restrict__ edge,   // 8192x1
    const float* __restrict__ weight, // 128x64
    const float* __restrict__ att,    // 192x1
    const float* __restrict__ wedge,  // 1x64
    float* __restrict__ wh,           // 8192x64
    float* __restrict__ src,          // 8192
    float* __restrict__ dst)          // 8192
{
    __shared__ float hs[4][FIN];
    const int wave = threadIdx.x >> 6;
    const int lane = threadIdx.x & 63;
    const int row  = blockIdx.x * 4 + wave;

    // Stage h row in LDS (wave-local; no barrier needed, wave is lockstep)
    const float* hrow = h + row * FIN;
    hs[wave][lane]      = hrow[lane];
    hs[wave][lane + 64] = hrow[lane + 64];

    float acc = 0.f;
#pragma unroll 8
    for (int c = 0; c < FIN; ++c)
        acc = fmaf(hs[wave][c], weight[c * FOUT + lane], acc);
    wh[row * FOUT + lane] = acc;

    float t1 = acc * att[lane];
    float t2 = acc * att[FOUT + lane];
    float t3 = wedge[lane] * att[2 * FOUT + lane];
#pragma unroll
    for (int off = 32; off > 0; off >>= 1) {
        t1 += __shfl_xor(t1, off, 64);
        t2 += __shfl_xor(t2, off, 64);
        t3 += __shfl_xor(t3, off, 64);
    }
    if (lane == 0) {
        src[row] = t1 + edge[row] * t3;
        dst[row] = t2;
    }
}

// Kernel B: fused masked-softmax + attention@wh + elu.
// No max-subtraction: v = lrelu(src+dst) bounded (~[-3,12]); exp(v) safe in fp32,
// masked entries contribute exactly 0 — identical result to reference softmax.
__global__ __launch_bounds__(256) void gat_attn(
    const int* __restrict__ adj,     // 8192x8192
    const float* __restrict__ wh,    // 8192x64
    const float* __restrict__ src,   // 8192
    const float* __restrict__ dst,   // 8192
    float* __restrict__ out)         // 8192x64
{
    __shared__ float P[16][64];
    const int wave = threadIdx.x >> 6;
    const int lane = threadIdx.x & 63;
    const int i0 = blockIdx.x * 16;
    const int r0 = wave * 4;

    const float s0 = src[i0 + r0 + 0];
    const float s1 = src[i0 + r0 + 1];
    const float s2 = src[i0 + r0 + 2];
    const float s3 = src[i0 + r0 + 3];
    const int* ap0 = adj + (size_t)(i0 + r0 + 0) * NN;
    const int* ap1 = adj + (size_t)(i0 + r0 + 1) * NN;
    const int* ap2 = adj + (size_t)(i0 + r0 + 2) * NN;
    const int* ap3 = adj + (size_t)(i0 + r0 + 3) * NN;

    float acc0 = 0.f, acc1 = 0.f, acc2 = 0.f, acc3 = 0.f;
    float l0 = 0.f, l1 = 0.f, l2 = 0.f, l3 = 0.f;

    for (int j0 = 0; j0 < NN; j0 += 64) {
        // Phase 1: lanes = j. Coalesced adj/dst reads; P tile -> LDS.
        const float dv = dst[j0 + lane];
        {
            float v, p;
            v = s0 + dv; v = fmaxf(v, LRELU_ALPHA * v);
            p = (ap0[j0 + lane] > 0) ? __expf(v) : 0.f;
            l0 += p; P[r0 + 0][lane] = p;

            v = s1 + dv; v = fmaxf(v, LRELU_ALPHA * v);
            p = (ap1[j0 + lane] > 0) ? __expf(v) : 0.f;
            l1 += p; P[r0 + 1][lane] = p;

            v = s2 + dv; v = fmaxf(v, LRELU_ALPHA * v);
            p = (ap2[j0 + lane] > 0) ? __expf(v) : 0.f;
            l2 += p; P[r0 + 2][lane] = p;

            v = s3 + dv; v = fmaxf(v, LRELU_ALPHA * v);
            p = (ap3[j0 + lane] > 0) ? __expf(v) : 0.f;
            l3 += p; P[r0 + 3][lane] = p;
        }
        __syncthreads();

        // Phase 2: lanes = feature k. LDS-broadcast p (float4), coalesced wh rows.
        const float* whp = wh + (size_t)j0 * FOUT + lane;
#pragma unroll
        for (int g = 0; g < 16; ++g) {
            const float4 p0 = *(const float4*)&P[r0 + 0][g * 4];
            const float4 p1 = *(const float4*)&P[r0 + 1][g * 4];
            const float4 p2 = *(const float4*)&P[r0 + 2][g * 4];
            const float4 p3 = *(const float4*)&P[r0 + 3][g * 4];
            const float w0 = whp[(g * 4 + 0) * FOUT];
            const float w1 = whp[(g * 4 + 1) * FOUT];
            const float w2 = whp[(g * 4 + 2) * FOUT];
            const float w3 = whp[(g * 4 + 3) * FOUT];
            acc0 += p0.x * w0 + p0.y * w1 + p0.z * w2 + p0.w * w3;
            acc1 += p1.x * w0 + p1.y * w1 + p1.z * w2 + p1.w * w3;
            acc2 += p2.x * w0 + p2.y * w1 + p2.z * w2 + p2.w * w3;
            acc3 += p3.x * w0 + p3.y * w1 + p3.z * w2 + p3.w * w3;
        }
        __syncthreads();
    }

    // Reduce softmax denominators across lanes (lane = j partials)
#pragma unroll
    for (int off = 32; off > 0; off >>= 1) {
        l0 += __shfl_xor(l0, off, 64);
        l1 += __shfl_xor(l1, off, 64);
        l2 += __shfl_xor(l2, off, 64);
        l3 += __shfl_xor(l3, off, 64);
    }

    float v;
    v = acc0 / l0; v = (v > 0.f) ? v : expm1f(v);
    out[(i0 + r0 + 0) * FOUT + lane] = v;
    v = acc1 / l1; v = (v > 0.f) ? v : expm1f(v);
    out[(i0 + r0 + 1) * FOUT + lane] = v;
    v = acc2 / l2; v = (v > 0.f) ? v : expm1f(v);
    out[(i0 + r0 + 2) * FOUT + lane] = v;
    v = acc3 / l3; v = (v > 0.f) ? v : expm1f(v);
    out[(i0 + r0 + 3) * FOUT + lane] = v;
}

extern "C" void kernel_launch(void* const* d_in, const int* in_sizes, int n_in,
                              void* d_out, int out_size, void* d_ws, size_t ws_size,
                              hipStream_t stream) {
    const float* h      = (const float*)d_in[0];
    const float* edge   = (const float*)d_in[1];
    const int*   adj    = (const int*)d_in[2];
    const float* weight = (const float*)d_in[3];
    const float* att    = (const float*)d_in[4];
    const float* wedge  = (const float*)d_in[5];
    float* out = (float*)d_out;

    float* wh  = (float*)d_ws;          // 8192*64 fp32 = 2 MB
    float* src = wh + NN * FOUT;        // 32 KB
    float* dst = src + NN;              // 32 KB

    gat_prep<<<NN / 4, 256, 0, stream>>>(h, edge, weight, att, wedge, wh, src, dst);
    gat_attn<<<NN / 16, 256, 0, stream>>>(adj, wh, src, dst, out);
}

// Round 3
// 415.896 us; speedup vs baseline: 1.7971x; 1.7971x over previous
//
#include <hip/hip_runtime.h>

#define NN 8192
#define FIN 128
#define FOUT 64
#define NSLICE 4
#define JSLICE (NN / NSLICE)

typedef __attribute__((ext_vector_type(8))) short short8;
typedef __attribute__((ext_vector_type(4))) float floatx4;

__device__ __forceinline__ unsigned short f32_to_bf16(float f) {
    unsigned int u = __float_as_uint(f);
    return (unsigned short)((u + 0x7FFFu + ((u >> 16) & 1u)) >> 16);
}
__device__ __forceinline__ float bf16_to_f32(unsigned short b) {
    return __uint_as_float(((unsigned int)b) << 16);
}

// Kernel 1: wh = h @ W (fp32, 16 rows/block, weight staged in LDS),
// src[i] = wh[i].a1 + edge[i]*(wedge.a3), dst[i] = wh[i].a2
__global__ __launch_bounds__(256) void gat_prep(
    const float* __restrict__ h,      // 8192x128
    const float* __restrict__ edge,   // 8192x1
    const float* __restrict__ weight, // 128x64
    const float* __restrict__ att,    // 192x1
    const float* __restrict__ wedge,  // 1x64
    float* __restrict__ wh,           // 8192x64 fp32
    float* __restrict__ src,          // 8192
    float* __restrict__ dst)          // 8192
{
    __shared__ float wl[FIN * FOUT];   // 32 KB
    __shared__ float hl[16 * FIN];     // 8 KB
    const int tid = threadIdx.x;

    const float4* w4 = (const float4*)weight;
    float4* wl4 = (float4*)wl;
    for (int idx = tid; idx < FIN * FOUT / 4; idx += 256) wl4[idx] = w4[idx];
    const float4* h4 = (const float4*)(h + (size_t)blockIdx.x * 16 * FIN);
    float4* hl4 = (float4*)hl;
    for (int idx = tid; idx < 16 * FIN / 4; idx += 256) hl4[idx] = h4[idx];
    __syncthreads();

    const int wave = tid >> 6;
    const int lane = tid & 63;
    float acc[4] = {0.f, 0.f, 0.f, 0.f};
    for (int c = 0; c < FIN; ++c) {
        const float wv = wl[c * FOUT + lane];
#pragma unroll
        for (int r = 0; r < 4; ++r)
            acc[r] = fmaf(hl[(wave * 4 + r) * FIN + c], wv, acc[r]);
    }
    const int row0 = blockIdx.x * 16 + wave * 4;
#pragma unroll
    for (int r = 0; r < 4; ++r)
        wh[(size_t)(row0 + r) * FOUT + lane] = acc[r];

    const float a1 = att[lane];
    const float a2 = att[FOUT + lane];
    float t3 = wedge[lane] * att[2 * FOUT + lane];
#pragma unroll
    for (int off = 32; off > 0; off >>= 1) t3 += __shfl_xor(t3, off, 64);

#pragma unroll
    for (int r = 0; r < 4; ++r) {
        float t1 = acc[r] * a1;
        float t2 = acc[r] * a2;
#pragma unroll
        for (int off = 32; off > 0; off >>= 1) {
            t1 += __shfl_xor(t1, off, 64);
            t2 += __shfl_xor(t2, off, 64);
        }
        if (lane == 0) {
            src[row0 + r] = t1 + edge[row0 + r] * t3;
            dst[row0 + r] = t2;
        }
    }
}

// Kernel 2: repack wh (fp32 row-major) into bf16 B-fragment order for
// mfma_f32_16x16x32_bf16: B[k=j][n=col], lane l holds B[c*32+(l>>4)*8+i][q*16+(l&15)].
// whB element (short8 units): [(T*8 + q*2 + c)*64 + l]
__global__ __launch_bounds__(256) void gat_repack(
    const float* __restrict__ wh, unsigned short* __restrict__ whB)
{
    const int T = blockIdx.x;          // j-tile of 64 rows of wh
    const int q = threadIdx.x >> 6;    // k-chunk 0..3
    const int l = threadIdx.x & 63;
    const int quad = l >> 4, col = l & 15;
#pragma unroll
    for (int c = 0; c < 2; ++c) {
        short8 frag;
#pragma unroll
        for (int i = 0; i < 8; ++i) {
            const int n = T * 64 + c * 32 + quad * 8 + i;
            frag[i] = (short)f32_to_bf16(wh[(size_t)n * FOUT + q * 16 + col]);
        }
        *(short8*)(whB + ((size_t)((T * 8 + q * 2 + c) * 64 + l)) * 8) = frag;
    }
}

// Kernel 3: fused masked-softmax-numerator + P@Wh via MFMA.
// Grid (512 i-blocks, 4 j-slices). Block = 4 waves; wave w: phase1 rows 4w..4w+3,
// phase2 k-chunk w of the 16x64 output tile. No max-subtraction needed:
// v = lrelu(src+dst) bounded (~[-4,12]); exp safe in fp32/bf16.
// l accumulated from bf16-ROUNDED p so numerator/denominator stay consistent.
__global__ __launch_bounds__(256) void gat_attn(
    const int* __restrict__ adj,
    const unsigned short* __restrict__ whB,
    const float* __restrict__ src,
    const float* __restrict__ dst,
    float* __restrict__ ws_acc,      // [4][8192][64]
    float* __restrict__ ws_l)        // [4][8192]
{
    __shared__ unsigned short Pt[16][72];  // +8 pad: 2-way bank aliasing (free)
    const int wave = threadIdx.x >> 6;
    const int lane = threadIdx.x & 63;
    const int i0 = blockIdx.x * 16;
    const int s  = blockIdx.y;
    const size_t jbase = (size_t)s * JSLICE;
    const int m = lane & 15, quad = lane >> 4;

    float sr[4];
    const int* ap[4];
#pragma unroll
    for (int r = 0; r < 4; ++r) {
        sr[r] = src[i0 + wave * 4 + r];
        ap[r] = adj + (size_t)(i0 + wave * 4 + r) * NN + jbase;
    }
    float lsum[4] = {0.f, 0.f, 0.f, 0.f};
    floatx4 acc = {0.f, 0.f, 0.f, 0.f};

    for (int j0 = 0; j0 < JSLICE; j0 += 64) {
        const float dv = dst[jbase + j0 + lane];
#pragma unroll
        for (int r = 0; r < 4; ++r) {
            float v = sr[r] + dv;
            v = fmaxf(v, 0.2f * v);
            const float p = (ap[r][j0 + lane] > 0) ? __expf(v) : 0.f;
            const unsigned short pb = f32_to_bf16(p);
            lsum[r] += bf16_to_f32(pb);
            Pt[wave * 4 + r][lane] = pb;
        }
        __syncthreads();

        // A-fragments from LDS: A[m][k=c*32+quad*8+i]
        const short8 a0 = *(const short8*)&Pt[m][quad * 8];
        const short8 a1 = *(const short8*)&Pt[m][32 + quad * 8];
        // B-fragments from pre-swizzled whB (coalesced dwordx4)
        const short8* bp = (const short8*)whB
                         + ((size_t)(((jbase + j0) >> 6) * 8 + wave * 2)) * 64 + lane;
        const short8 b0 = bp[0];
        const short8 b1 = bp[64];
        acc = __builtin_amdgcn_mfma_f32_16x16x32_bf16(a0, b0, acc, 0, 0, 0);
        acc = __builtin_amdgcn_mfma_f32_16x16x32_bf16(a1, b1, acc, 0, 0, 0);
        __syncthreads();
    }

#pragma unroll
    for (int r = 0; r < 4; ++r) {
#pragma unroll
        for (int off = 32; off > 0; off >>= 1)
            lsum[r] += __shfl_xor(lsum[r], off, 64);
    }
    if (lane == 0) {
#pragma unroll
        for (int r = 0; r < 4; ++r)
            ws_l[(size_t)s * NN + i0 + wave * 4 + r] = lsum[r];
    }

    // C/D layout: col = lane&15, row = quad*4 + reg
#pragma unroll
    for (int reg = 0; reg < 4; ++reg) {
        const int row = quad * 4 + reg;
        ws_acc[(size_t)s * (NN * FOUT) + (size_t)(i0 + row) * FOUT + wave * 16 + m] = acc[reg];
    }
}

// Kernel 4: reduce the 4 j-slices, divide by softmax denom, ELU.
__global__ __launch_bounds__(256) void gat_finish(
    const float* __restrict__ ws_acc, const float* __restrict__ ws_l,
    float* __restrict__ out)
{
    const int idx = blockIdx.x * 256 + threadIdx.x;   // 0 .. 8192*64-1
    const int i = idx >> 6;
    float a = 0.f, l = 0.f;
#pragma unroll
    for (int s = 0; s < NSLICE; ++s) {
        a += ws_acc[(size_t)s * (NN * FOUT) + idx];
        l += ws_l[(size_t)s * NN + i];
    }
    float v = a / l;
    out[idx] = (v > 0.f) ? v : expm1f(v);
}

extern "C" void kernel_launch(void* const* d_in, const int* in_sizes, int n_in,
                              void* d_out, int out_size, void* d_ws, size_t ws_size,
                              hipStream_t stream) {
    const float* h      = (const float*)d_in[0];
    const float* edge   = (const float*)d_in[1];
    const int*   adj    = (const int*)d_in[2];
    const float* weight = (const float*)d_in[3];
    const float* att    = (const float*)d_in[4];
    const float* wedge  = (const float*)d_in[5];
    float* out = (float*)d_out;

    float* wh     = (float*)d_ws;                 // 8192*64 fp32    (2 MB)
    float* src    = wh + (size_t)NN * FOUT;       // 8192
    float* dst    = src + NN;                     // 8192
    float* ws_l   = dst + NN;                     // 4*8192          (128 KB)
    float* ws_acc = ws_l + (size_t)NSLICE * NN;   // 4*8192*64 fp32  (8 MB)
    unsigned short* whB = (unsigned short*)(ws_acc + (size_t)NSLICE * NN * FOUT); // 1 MB

    gat_prep<<<NN / 16, 256, 0, stream>>>(h, edge, weight, att, wedge, wh, src, dst);
    gat_repack<<<NN / 64, 256, 0, stream>>>(wh, whB);
    gat_attn<<<dim3(NN / 16, NSLICE), 256, 0, stream>>>(adj, whB, src, dst, ws_acc, ws_l);
    gat_finish<<<NN * FOUT / 256, 256, 0, stream>>>(ws_acc, ws_l, out);
}

// Round 4
// 385.043 us; speedup vs baseline: 1.9411x; 1.0801x over previous
//
#include <hip/hip_runtime.h>

#define NN 8192
#define FIN 128
#define FOUT 64
#define NSLICE 4
#define JSLICE (NN / NSLICE)
#define JTILE 256
#define PT_LD 264   // Pt row stride in shorts: 256 + 8 pad (keeps 4(m+quad) bank pattern)

typedef __attribute__((ext_vector_type(8))) short short8;
typedef __attribute__((ext_vector_type(4))) float floatx4;
typedef __attribute__((ext_vector_type(4))) unsigned short ushort4v;

__device__ __forceinline__ unsigned short f32_to_bf16(float f) {
    unsigned int u = __float_as_uint(f);
    return (unsigned short)((u + 0x7FFFu + ((u >> 16) & 1u)) >> 16);
}
__device__ __forceinline__ float bf16_to_f32(unsigned short b) {
    return __uint_as_float(((unsigned int)b) << 16);
}

// Kernel 1: wh = h @ W (fp32), src[i] = wh[i].a1 + edge[i]*(wedge.a3), dst[i] = wh[i].a2
__global__ __launch_bounds__(256) void gat_prep(
    const float* __restrict__ h,      // 8192x128
    const float* __restrict__ edge,   // 8192x1
    const float* __restrict__ weight, // 128x64
    const float* __restrict__ att,    // 192x1
    const float* __restrict__ wedge,  // 1x64
    float* __restrict__ wh,           // 8192x64 fp32
    float* __restrict__ src,          // 8192
    float* __restrict__ dst)          // 8192
{
    __shared__ float wl[FIN * FOUT];   // 32 KB
    __shared__ float hl[16 * FIN];     // 8 KB
    const int tid = threadIdx.x;

    const float4* w4 = (const float4*)weight;
    float4* wl4 = (float4*)wl;
    for (int idx = tid; idx < FIN * FOUT / 4; idx += 256) wl4[idx] = w4[idx];
    const float4* h4 = (const float4*)(h + (size_t)blockIdx.x * 16 * FIN);
    float4* hl4 = (float4*)hl;
    for (int idx = tid; idx < 16 * FIN / 4; idx += 256) hl4[idx] = h4[idx];
    __syncthreads();

    const int wave = tid >> 6;
    const int lane = tid & 63;
    float acc[4] = {0.f, 0.f, 0.f, 0.f};
    for (int c = 0; c < FIN; ++c) {
        const float wv = wl[c * FOUT + lane];
#pragma unroll
        for (int r = 0; r < 4; ++r)
            acc[r] = fmaf(hl[(wave * 4 + r) * FIN + c], wv, acc[r]);
    }
    const int row0 = blockIdx.x * 16 + wave * 4;
#pragma unroll
    for (int r = 0; r < 4; ++r)
        wh[(size_t)(row0 + r) * FOUT + lane] = acc[r];

    const float a1 = att[lane];
    const float a2 = att[FOUT + lane];
    float t3 = wedge[lane] * att[2 * FOUT + lane];
#pragma unroll
    for (int off = 32; off > 0; off >>= 1) t3 += __shfl_xor(t3, off, 64);

#pragma unroll
    for (int r = 0; r < 4; ++r) {
        float t1 = acc[r] * a1;
        float t2 = acc[r] * a2;
#pragma unroll
        for (int off = 32; off > 0; off >>= 1) {
            t1 += __shfl_xor(t1, off, 64);
            t2 += __shfl_xor(t2, off, 64);
        }
        if (lane == 0) {
            src[row0 + r] = t1 + edge[row0 + r] * t3;
            dst[row0 + r] = t2;
        }
    }
}

// Kernel 2: repack wh (fp32 row-major) -> bf16 B-fragment order for mfma_f32_16x16x32_bf16.
// Frag f = (T*8 + q*2 + c): lane l holds B[k=c*32+(l>>4)*8+i][q*16+(l&15)], i=0..7.
// Grid (128 T-tiles, 2 c-halves) x 256 threads: one short8 frag-lane per thread.
__global__ __launch_bounds__(256) void gat_repack(
    const float* __restrict__ wh, unsigned short* __restrict__ whB)
{
    const int T = blockIdx.x;
    const int c = blockIdx.y;
    const int q = threadIdx.x >> 6;
    const int l = threadIdx.x & 63;
    const int quad = l >> 4, col = l & 15;
    short8 frag;
#pragma unroll
    for (int i = 0; i < 8; ++i) {
        const int n = T * 64 + c * 32 + quad * 8 + i;
        frag[i] = (short)f32_to_bf16(wh[(size_t)n * FOUT + q * 16 + col]);
    }
    *(short8*)(whB + ((size_t)((T * 8 + q * 2 + c) * 64 + l)) * 8) = frag;
}

// Kernel 3: fused masked-softmax-numerator + P@Wh via MFMA, 256-j tiles.
// Grid (512 i-blocks, 4 j-slices), 4 waves/block. Wave w: phase1 rows 4w..4w+3
// (int4 adj, float4 dst, 4 j per lane), phase2 feature-chunk w, 8 MFMAs (K=256).
// No max-subtraction: v = lrelu(src+dst) bounded (~[-4,12]); exp safe in fp32.
// Denominator accumulated from bf16-ROUNDED p = consistent with MFMA numerator.
__global__ __launch_bounds__(256) void gat_attn(
    const int* __restrict__ adj,
    const unsigned short* __restrict__ whB,
    const float* __restrict__ src,
    const float* __restrict__ dst,
    float* __restrict__ ws_acc,      // [4][8192][64]
    float* __restrict__ ws_l)        // [4][8192]
{
    __shared__ unsigned short Pt[16][PT_LD];
    const int wave = threadIdx.x >> 6;
    const int lane = threadIdx.x & 63;
    const int i0 = blockIdx.x * 16;
    const int s  = blockIdx.y;
    const size_t jbase = (size_t)s * JSLICE;
    const int m = lane & 15, quad = lane >> 4;

    float sr[4];
    const int4* ap[4];
#pragma unroll
    for (int r = 0; r < 4; ++r) {
        sr[r] = src[i0 + wave * 4 + r];
        ap[r] = (const int4*)(adj + (size_t)(i0 + wave * 4 + r) * NN + jbase);
    }
    const float4* dst4 = (const float4*)(dst + jbase);
    float lsum[4] = {0.f, 0.f, 0.f, 0.f};
    floatx4 acc = {0.f, 0.f, 0.f, 0.f};

    for (int j0 = 0; j0 < JSLICE; j0 += JTILE) {
        // ---- Phase 1: lanes = j/4. 16 B adj loads, 4 p-values per lane per row.
        const float4 dv = dst4[(j0 >> 2) + lane];
#pragma unroll
        for (int r = 0; r < 4; ++r) {
            const int4 av = ap[r][(j0 >> 2) + lane];
            ushort4v pv;
            float v, p;
            v = sr[r] + dv.x; v = fmaxf(v, 0.2f * v);
            p = (av.x > 0) ? __expf(v) : 0.f; pv.x = f32_to_bf16(p);
            v = sr[r] + dv.y; v = fmaxf(v, 0.2f * v);
            p = (av.y > 0) ? __expf(v) : 0.f; pv.y = f32_to_bf16(p);
            v = sr[r] + dv.z; v = fmaxf(v, 0.2f * v);
            p = (av.z > 0) ? __expf(v) : 0.f; pv.z = f32_to_bf16(p);
            v = sr[r] + dv.w; v = fmaxf(v, 0.2f * v);
            p = (av.w > 0) ? __expf(v) : 0.f; pv.w = f32_to_bf16(p);
            lsum[r] += bf16_to_f32(pv.x) + bf16_to_f32(pv.y)
                     + bf16_to_f32(pv.z) + bf16_to_f32(pv.w);
            *(ushort4v*)&Pt[wave * 4 + r][4 * lane] = pv;
        }
        __syncthreads();

        // ---- Phase 2: 8 MFMAs over K=256. A from LDS, B pre-swizzled (coalesced).
        const int jt0 = (int)((jbase + j0) >> 6);
#pragma unroll
        for (int kk = 0; kk < 8; ++kk) {
            const short8 a = *(const short8*)&Pt[m][kk * 32 + quad * 8];
            const int f = (jt0 + (kk >> 1)) * 8 + wave * 2 + (kk & 1);
            const short8 b = *((const short8*)whB + (size_t)f * 64 + lane);
            acc = __builtin_amdgcn_mfma_f32_16x16x32_bf16(a, b, acc, 0, 0, 0);
        }
        __syncthreads();
    }

#pragma unroll
    for (int r = 0; r < 4; ++r) {
#pragma unroll
        for (int off = 32; off > 0; off >>= 1)
            lsum[r] += __shfl_xor(lsum[r], off, 64);
    }
    if (lane == 0) {
#pragma unroll
        for (int r = 0; r < 4; ++r)
            ws_l[(size_t)s * NN + i0 + wave * 4 + r] = lsum[r];
    }

    // C/D layout: col = lane&15, row = quad*4 + reg
#pragma unroll
    for (int reg = 0; reg < 4; ++reg) {
        const int row = quad * 4 + reg;
        ws_acc[(size_t)s * (NN * FOUT) + (size_t)(i0 + row) * FOUT + wave * 16 + m] = acc[reg];
    }
}

// Kernel 4: reduce 4 j-slices, divide by softmax denom, ELU.
__global__ __launch_bounds__(256) void gat_finish(
    const float* __restrict__ ws_acc, const float* __restrict__ ws_l,
    float* __restrict__ out)
{
    const int idx = blockIdx.x * 256 + threadIdx.x;   // 0 .. 8192*64-1
    const int i = idx >> 6;
    float a = 0.f, l = 0.f;
#pragma unroll
    for (int s = 0; s < NSLICE; ++s) {
        a += ws_acc[(size_t)s * (NN * FOUT) + idx];
        l += ws_l[(size_t)s * NN + i];
    }
    float v = a / l;
    out[idx] = (v > 0.f) ? v : expm1f(v);
}

extern "C" void kernel_launch(void* const* d_in, const int* in_sizes, int n_in,
                              void* d_out, int out_size, void* d_ws, size_t ws_size,
                              hipStream_t stream) {
    const float* h      = (const float*)d_in[0];
    const float* edge   = (const float*)d_in[1];
    const int*   adj    = (const int*)d_in[2];
    const float* weight = (const float*)d_in[3];
    const float* att    = (const float*)d_in[4];
    const float* wedge  = (const float*)d_in[5];
    float* out = (float*)d_out;

    float* wh     = (float*)d_ws;                 // 8192*64 fp32    (2 MB)
    float* src    = wh + (size_t)NN * FOUT;       // 8192
    float* dst    = src + NN;                     // 8192
    float* ws_l   = dst + NN;                     // 4*8192          (128 KB)
    float* ws_acc = ws_l + (size_t)NSLICE * NN;   // 4*8192*64 fp32  (8 MB)
    unsigned short* whB = (unsigned short*)(ws_acc + (size_t)NSLICE * NN * FOUT); // 1 MB

    gat_prep<<<NN / 16, 256, 0, stream>>>(h, edge, weight, att, wedge, wh, src, dst);
    gat_repack<<<dim3(NN / 64, 2), 256, 0, stream>>>(wh, whB);
    gat_attn<<<dim3(NN / 16, NSLICE), 256, 0, stream>>>(adj, whB, src, dst, ws_acc, ws_l);
    gat_finish<<<NN * FOUT / 256, 256, 0, stream>>>(ws_acc, ws_l, out);
}

// Round 5
// 378.069 us; speedup vs baseline: 1.9769x; 1.0184x over previous
//
#include <hip/hip_runtime.h>

#define NN 8192
#define FIN 128
#define FOUT 64
#define NSLICE 4
#define JSLICE (NN / NSLICE)
#define JTILE 256
#define NT (JSLICE / JTILE)   // 8 tiles per block
#define PT_LD 264             // Pt row stride in shorts: 256 + 8 pad

typedef __attribute__((ext_vector_type(8))) short short8;
typedef __attribute__((ext_vector_type(4))) float floatx4;
typedef __attribute__((ext_vector_type(4))) unsigned short ushort4v;

__device__ __forceinline__ unsigned short f32_to_bf16(float f) {
    unsigned int u = __float_as_uint(f);
    return (unsigned short)((u + 0x7FFFu + ((u >> 16) & 1u)) >> 16);
}
__device__ __forceinline__ float bf16_to_f32(unsigned short b) {
    return __uint_as_float(((unsigned int)b) << 16);
}

// Kernel 1: wh = h @ W (fp32). Writes whB DIRECTLY in MFMA B-fragment order
// (bf16), plus src[i] = wh[i].a1 + edge[i]*(wedge.a3), dst[i] = wh[i].a2.
// B-frag layout (verified r3/r4): whB[(f*64 + l)*8 + i] = bf16(wh[row][feat]),
// f = T*8 + q*2 + c, row = T*64 + c*32 + (l>>4)*8 + i, feat = q*16 + (l&15).
// Block b owns rows b*16..b*16+15: T=b>>2 const; wave w rows r0=b*16+w*4..+3
// give i = (w&1)*4 + r (4 consecutive) -> one aligned 8B ushort4 store/thread.
__global__ __launch_bounds__(256) void gat_prep(
    const float* __restrict__ h,      // 8192x128
    const float* __restrict__ edge,   // 8192x1
    const float* __restrict__ weight, // 128x64
    const float* __restrict__ att,    // 192x1
    const float* __restrict__ wedge,  // 1x64
    unsigned short* __restrict__ whB, // bf16 fragment-order (1 MB)
    float* __restrict__ src,          // 8192
    float* __restrict__ dst)          // 8192
{
    __shared__ float wl[FIN * FOUT];   // 32 KB
    __shared__ float hl[16 * FIN];     // 8 KB
    const int tid = threadIdx.x;
    const int b = blockIdx.x;

    const float4* w4 = (const float4*)weight;
    float4* wl4 = (float4*)wl;
    for (int idx = tid; idx < FIN * FOUT / 4; idx += 256) wl4[idx] = w4[idx];
    const float4* h4 = (const float4*)(h + (size_t)b * 16 * FIN);
    float4* hl4 = (float4*)hl;
    for (int idx = tid; idx < 16 * FIN / 4; idx += 256) hl4[idx] = h4[idx];
    __syncthreads();

    const int wave = tid >> 6;
    const int lane = tid & 63;
    float acc[4] = {0.f, 0.f, 0.f, 0.f};
    for (int c = 0; c < FIN; ++c) {
        const float wv = wl[c * FOUT + lane];
#pragma unroll
        for (int r = 0; r < 4; ++r)
            acc[r] = fmaf(hl[(wave * 4 + r) * FIN + c], wv, acc[r]);
    }
    const int row0 = b * 16 + wave * 4;

    // ---- whB fragment-order store ----
    {
        const int T = b >> 2;
        const int o = (b & 3) * 16 + wave * 4;     // tile-local row of r=0
        const int c = o >> 5;
        const int quad = (o >> 3) & 3;
        const int i0 = o & 7;                      // 0 or 4
        const int q = lane >> 4, col = lane & 15;
        const int f = T * 8 + q * 2 + c;
        const int elem = f * 64 + quad * 16 + col;
        ushort4v wb;
#pragma unroll
        for (int r = 0; r < 4; ++r) wb[r] = f32_to_bf16(acc[r]);
        *(ushort4v*)(whB + (size_t)elem * 8 + i0) = wb;
    }

    const float a1 = att[lane];
    const float a2 = att[FOUT + lane];
    float t3 = wedge[lane] * att[2 * FOUT + lane];
#pragma unroll
    for (int off = 32; off > 0; off >>= 1) t3 += __shfl_xor(t3, off, 64);

#pragma unroll
    for (int r = 0; r < 4; ++r) {
        float t1 = acc[r] * a1;
        float t2 = acc[r] * a2;
#pragma unroll
        for (int off = 32; off > 0; off >>= 1) {
            t1 += __shfl_xor(t1, off, 64);
            t2 += __shfl_xor(t2, off, 64);
        }
        if (lane == 0) {
            src[row0 + r] = t1 + edge[row0 + r] * t3;
            dst[row0 + r] = t2;
        }
    }
}

// Kernel 2: fused masked-softmax-numerator + P@Wh via MFMA, software-pipelined.
// Grid (512 i-blocks, 4 j-slices), 4 waves. Per 256-j tile: exp-compute from
// prefetched regs -> LDS (double-buffered), register-prefetch of NEXT tile's
// adj/dst, then raw lgkmcnt(0)+s_barrier (no vmcnt drain -> prefetch stays in
// flight across the barrier), then 8 MFMAs (K=256). One barrier per tile:
// buf[t&1] is rewritten only at t+2, after barrier t+1, by which time every
// wave's tile-t LDS reads have been consumed (lgkmcnt-waited before MFMA).
__global__ __launch_bounds__(256) void gat_attn(
    const int* __restrict__ adj,
    const unsigned short* __restrict__ whB,
    const float* __restrict__ src,
    const float* __restrict__ dst,
    float* __restrict__ ws_acc,      // [4][8192][64]
    float* __restrict__ ws_l)        // [4][8192]
{
    __shared__ unsigned short Pt[2][16][PT_LD];   // 16.9 KB
    const int wave = threadIdx.x >> 6;
    const int lane = threadIdx.x & 63;
    const int i0 = blockIdx.x * 16;
    const int s  = blockIdx.y;
    const size_t jbase = (size_t)s * JSLICE;
    const int m = lane & 15, quad = lane >> 4;

    float sr[4];
    const int4* ap[4];
#pragma unroll
    for (int r = 0; r < 4; ++r) {
        sr[r] = src[i0 + wave * 4 + r];
        ap[r] = (const int4*)(adj + (size_t)(i0 + wave * 4 + r) * NN + jbase);
    }
    const float4* dst4 = (const float4*)(dst + jbase);
    float lsum[4] = {0.f, 0.f, 0.f, 0.f};
    floatx4 acc = {0.f, 0.f, 0.f, 0.f};

    // Preload tile 0
    int4 av[4];
    float4 dv = dst4[lane];
#pragma unroll
    for (int r = 0; r < 4; ++r) av[r] = ap[r][lane];

    for (int t = 0; t < NT; ++t) {
        const int buf = t & 1;

        // ---- exp-compute current tile from registers; write LDS
#pragma unroll
        for (int r = 0; r < 4; ++r) {
            ushort4v pv;
            float v, p;
            v = sr[r] + dv.x; v = fmaxf(v, 0.2f * v);
            p = (av[r].x > 0) ? __expf(v) : 0.f; pv.x = f32_to_bf16(p);
            v = sr[r] + dv.y; v = fmaxf(v, 0.2f * v);
            p = (av[r].y > 0) ? __expf(v) : 0.f; pv.y = f32_to_bf16(p);
            v = sr[r] + dv.z; v = fmaxf(v, 0.2f * v);
            p = (av[r].z > 0) ? __expf(v) : 0.f; pv.z = f32_to_bf16(p);
            v = sr[r] + dv.w; v = fmaxf(v, 0.2f * v);
            p = (av[r].w > 0) ? __expf(v) : 0.f; pv.w = f32_to_bf16(p);
            lsum[r] += bf16_to_f32(pv.x) + bf16_to_f32(pv.y)
                     + bf16_to_f32(pv.z) + bf16_to_f32(pv.w);
            *(ushort4v*)&Pt[buf][wave * 4 + r][4 * lane] = pv;
        }

        // ---- prefetch next tile (stays in flight across raw barrier + MFMAs)
        if (t + 1 < NT) {
            const int o = (t + 1) * (JTILE / 4) + lane;
            dv = dst4[o];
#pragma unroll
            for (int r = 0; r < 4; ++r) av[r] = ap[r][o];
        }

        // ---- LDS-visibility barrier only (no vmcnt drain)
        __builtin_amdgcn_s_waitcnt(0xC07F);   // lgkmcnt(0)
        __builtin_amdgcn_s_barrier();

        // ---- 8 MFMAs over K=256. A from LDS, B pre-swizzled (coalesced, L2-hit)
        const int jt0 = (int)((jbase + (size_t)t * JTILE) >> 6);
#pragma unroll
        for (int kk = 0; kk < 8; ++kk) {
            const short8 a = *(const short8*)&Pt[buf][m][kk * 32 + quad * 8];
            const int f = (jt0 + (kk >> 1)) * 8 + wave * 2 + (kk & 1);
            const short8 bfr = *((const short8*)whB + (size_t)f * 64 + lane);
            acc = __builtin_amdgcn_mfma_f32_16x16x32_bf16(a, bfr, acc, 0, 0, 0);
        }
    }

#pragma unroll
    for (int r = 0; r < 4; ++r) {
#pragma unroll
        for (int off = 32; off > 0; off >>= 1)
            lsum[r] += __shfl_xor(lsum[r], off, 64);
    }
    if (lane == 0) {
#pragma unroll
        for (int r = 0; r < 4; ++r)
            ws_l[(size_t)s * NN + i0 + wave * 4 + r] = lsum[r];
    }

    // C/D layout: col = lane&15, row = quad*4 + reg
#pragma unroll
    for (int reg = 0; reg < 4; ++reg) {
        const int row = quad * 4 + reg;
        ws_acc[(size_t)s * (NN * FOUT) + (size_t)(i0 + row) * FOUT + wave * 16 + m] = acc[reg];
    }
}

// Kernel 3: reduce 4 j-slices, divide by softmax denom, ELU.
__global__ __launch_bounds__(256) void gat_finish(
    const float* __restrict__ ws_acc, const float* __restrict__ ws_l,
    float* __restrict__ out)
{
    const int idx = blockIdx.x * 256 + threadIdx.x;   // 0 .. 8192*64-1
    const int i = idx >> 6;
    float a = 0.f, l = 0.f;
#pragma unroll
    for (int s = 0; s < NSLICE; ++s) {
        a += ws_acc[(size_t)s * (NN * FOUT) + idx];
        l += ws_l[(size_t)s * NN + i];
    }
    float v = a / l;
    out[idx] = (v > 0.f) ? v : expm1f(v);
}

extern "C" void kernel_launch(void* const* d_in, const int* in_sizes, int n_in,
                              void* d_out, int out_size, void* d_ws, size_t ws_size,
                              hipStream_t stream) {
    const float* h      = (const float*)d_in[0];
    const float* edge   = (const float*)d_in[1];
    const int*   adj    = (const int*)d_in[2];
    const float* weight = (const float*)d_in[3];
    const float* att    = (const float*)d_in[4];
    const float* wedge  = (const float*)d_in[5];
    float* out = (float*)d_out;

    unsigned short* whB = (unsigned short*)d_ws;          // 1 MB bf16 frags
    float* src    = (float*)(whB + (size_t)NN * FOUT);    // 8192
    float* dst    = src + NN;                             // 8192
    float* ws_l   = dst + NN;                             // 4*8192
    float* ws_acc = ws_l + (size_t)NSLICE * NN;           // 8 MB

    gat_prep<<<NN / 16, 256, 0, stream>>>(h, edge, weight, att, wedge, whB, src, dst);
    gat_attn<<<dim3(NN / 16, NSLICE), 256, 0, stream>>>(adj, whB, src, dst, ws_acc, ws_l);
    gat_finish<<<NN * FOUT / 256, 256, 0, stream>>>(ws_acc, ws_l, out);
}